// Round 4
// baseline (846.176 us; speedup 1.0000x reference)
//
#include <hip/hip_runtime.h>
#include <cstdint>

typedef _Float16 half_t;
typedef _Float16 half8  __attribute__((ext_vector_type(8)));
typedef _Float16 half4_t __attribute__((ext_vector_type(4)));
typedef _Float16 h2f    __attribute__((ext_vector_type(2)));
typedef float    floatx4 __attribute__((ext_vector_type(4)));

#define KNN 40
#define KVPAD 124

// ---------------- workspace layout (bytes) ----------------
#define WS_NF16    0ull
#define WS_EMB16   25600000ull
#define WS_WKVT    28672000ull
#define WS_WQ4     29065216ull
#define WS_W1A4    29196288ull
#define WS_W1B4    29327360ull
#define WS_W24     29458432ull
#define WS_QBIAS   29589504ull
#define WS_EF16    29721856ull

// global -> LDS direct copy, 16 B per lane, dest = wave-uniform base + lane*16
__device__ __forceinline__ void ld16(const void* g, void* l) {
  __builtin_amdgcn_global_load_lds(
      (const __attribute__((address_space(1))) unsigned int*)(uintptr_t)g,
      (__attribute__((address_space(3))) unsigned int*)(uintptr_t)l, 16, 0, 0);
}

__device__ __forceinline__ float dot4(half4_t a, half4_t b, float s) {
  s = __builtin_amdgcn_fdot2((h2f){a[0], a[1]}, (h2f){b[0], b[1]}, s, false);
  s = __builtin_amdgcn_fdot2((h2f){a[2], a[3]}, (h2f){b[2], b[3]}, s, false);
  return s;
}

// ---------------------------------------------------------------------------
__global__ __launch_bounds__(256) void cvt_kernel(
    const float* __restrict__ src, half_t* __restrict__ dst, int n8) {
  int stride = gridDim.x * 256;
  for (int i = blockIdx.x * 256 + threadIdx.x; i < n8; i += stride) {
    float4 a = *((const float4*)src + 2 * (size_t)i);
    float4 b = *((const float4*)src + 2 * (size_t)i + 1);
    half8 h;
    h[0] = (half_t)a.x; h[1] = (half_t)a.y; h[2] = (half_t)a.z; h[3] = (half_t)a.w;
    h[4] = (half_t)b.x; h[5] = (half_t)b.y; h[6] = (half_t)b.z; h[7] = (half_t)b.w;
    *((half8*)dst + i) = h;
  }
}

// decode t -> (l, d4, j, e): packed idx = l*16384 + (d4*128+j)*4 + e
#define PK_DECODE(t) int l = (t) >> 14; int u = (t) & 16383; \
  int d4 = u >> 9; int v = u & 511; int j = v >> 2; int e = v & 3;

__global__ __launch_bounds__(256) void precompute_w(
    const float* __restrict__ Wq, const float* __restrict__ Wk,
    const float* __restrict__ Wv, const float* __restrict__ Wo,
    const float* __restrict__ fc1, const float* __restrict__ fc2,
    const float* __restrict__ time_b,
    half_t* __restrict__ WkvT, float* __restrict__ qbias,
    half_t* __restrict__ Wq4, half_t* __restrict__ W1a4,
    half_t* __restrict__ W1b4, half_t* __restrict__ W24)
{
  int blk = blockIdx.x, tid = threadIdx.x;
  if (blk < 768) {
    int t = blk * 256 + tid;            // [0, 2*256*384)
    int l = t / 98304;
    int r = t - l * 98304;
    int n = r / 384;
    int k = r - n * 384;
    float vv = (n < 128) ? Wk[l * 49152 + k * 128 + n]
                         : Wv[l * 49152 + k * 128 + (n - 128)];
    WkvT[t] = (half_t)vv;
  } else if (blk == 768) {
    int l = tid >> 7, j = tid & 127;
    float s = 0.f;
    for (int d = 0; d < 128; ++d)
      s += cosf(time_b[d]) * Wq[l * 32768 + (128 + d) * 128 + j];
    qbias[l * 128 + j] = s;
  } else if (blk < 897) {               // W1a4 = (Wo @ fc1_top) packed
    int t = (blk - 769) * 256 + tid;
    PK_DECODE(t);
    float s = 0.f;
    for (int m = 0; m < 128; ++m)
      s += Wo[l * 16384 + (4 * d4 + e) * 128 + m] * fc1[l * 32768 + m * 128 + j];
    W1a4[t] = (half_t)s;
  } else if (blk < 1025) {
    int t = (blk - 897) * 256 + tid;
    PK_DECODE(t);
    Wq4[t] = (half_t)Wq[l * 32768 + (4 * d4 + e) * 128 + j];
  } else if (blk < 1153) {
    int t = (blk - 1025) * 256 + tid;
    PK_DECODE(t);
    W1b4[t] = (half_t)fc1[l * 32768 + (128 + 4 * d4 + e) * 128 + j];
  } else {
    int t = (blk - 1153) * 256 + tid;
    PK_DECODE(t);
    W24[t] = (half_t)fc2[l * 16384 + (4 * d4 + e) * 128 + j];
  }
}

// ---------------------------------------------------------------------------
// Fused hop aggregation. 512 thr = 8 waves, 3 batches/block (120 kv rows).
// ALL A gathers prefetched via global_load_lds before ONE barrier; time-enc
// chunks computed in-register; B fragments read straight from L2-hot WkvT.
// K-loop is barrier-free so no s_waitcnt vmcnt(0) ever drains HBM gathers.
// ---------------------------------------------------------------------------
template <bool L1DIR>
__global__ __launch_bounds__(512, 4) void hop_kernel(
    const half_t* __restrict__ nf16,
    const half_t* __restrict__ ne16,     // L0: nf16 (gather); L1: emb116 direct
    const half_t* __restrict__ ef16,
    const int*    __restrict__ src_idx,
    const float*  __restrict__ tsv,
    const int*    __restrict__ neigh,
    const int*    __restrict__ eidx,
    const float*  __restrict__ etimes,
    const float*  __restrict__ tw,
    const float*  __restrict__ tb,
    const half_t* __restrict__ Wq4_l,
    const float*  __restrict__ qbias_l,
    const half_t* __restrict__ WkvT_l,
    const half_t* __restrict__ W1a4_l,
    const half_t* __restrict__ W1b4_l,
    const half_t* __restrict__ W24_l,
    half_t* __restrict__ out16,
    float*  __restrict__ out32)
{
  // LDS 71104 B -> 2 blocks/CU.
  //  A [4 grp][8 mt][8 c][16 r][8 f16] @0 (65536)  (grp: NF-k0, NF-k1, EF-k0, EF-k1)
  //  kvT [128 col][124 row] f16 @0 (reuses A after K-loop)
  //  @65536: tw_s 512 | tb_s 512 | dvals 512 | qs 1536 | scs 960 | aO16 768 | h116 768
  __shared__ __align__(16) char smem[71104];
  half_t* A    = (half_t*)smem;
  half_t* kvT  = (half_t*)smem;
  float*  tw_s = (float*)(smem + 65536);
  float*  tb_s = (float*)(smem + 66048);
  float*  dvals= (float*)(smem + 66560);
  float*  qs   = (float*)(smem + 67072);
  float*  scs  = (float*)(smem + 68608);
  half_t* aO16 = (half_t*)(smem + 69568);
  half_t* h116 = (half_t*)(smem + 70336);

  const int tid = threadIdx.x;
  const int bbase = blockIdx.x * 3;
  const int lane = tid & 63, wv = tid >> 6;
  const int l15 = lane & 15, q4 = lane >> 4;
  const int wm = (wv & 1) * 64, wn = (wv >> 1) * 64;

  if (tid < 128) { tw_s[tid] = tw[tid]; tb_s[tid] = tb[tid]; }

  // per-lane row (4-way q4 duplication), r = 0..127
  const int r = wv * 16 + l15;
  const bool valid = (r < 120);
  float dval = 0.f;
  const half_t* pNE = nf16;
  const half_t* pEF = nf16;
  if (valid) {
    int g = r / 40, n = r - g * 40;
    int bg = bbase + g;
    int rowidx = bg * KNN + n;
    dval = tsv[L1DIR ? bg : (bg / 40)] - etimes[rowidx];
    pNE = L1DIR ? ne16 + (size_t)rowidx * 128
                : ne16 + (size_t)neigh[rowidx] * 128;
    pEF = ef16 + (size_t)eidx[rowidx] * 128;
  }
  if (q4 == 0) dvals[r] = dval;
  pNE += q4 * 8; pEF += q4 * 8;

  // ---- issue ALL gathers (8 ld16/lane), fire-and-forget ----
  {
    char* d0 = smem + wv * 2048;
    ld16(pNE,      d0);
    ld16(pNE + 32, d0 + 1024);
    ld16(pNE + 64, d0 + 16384);
    ld16(pNE + 96, d0 + 16384 + 1024);
    ld16(pEF,      d0 + 32768);
    ld16(pEF + 32, d0 + 32768 + 1024);
    ld16(pEF + 64, d0 + 49152);
    ld16(pEF + 96, d0 + 49152 + 1024);
  }

  // ---- q = src @ Wq_top + qbias (global L2-hot reads, runs in gather shadow) ----
  if (tid < 384) {
    int gq = tid >> 7, jq = tid & 127;
    const half_t* srow = nf16 + (size_t)src_idx[bbase + gq] * 128;
    float s = qbias_l[jq];
    #pragma unroll 8
    for (int d4 = 0; d4 < 32; ++d4) {
      half4_t w = *(const half4_t*)(Wq4_l + (d4 * 128 + jq) * 4);
      half4_t a = *(const half4_t*)(srow + d4 * 4);
      s = dot4(w, a, s);
    }
    qs[gq * 128 + jq] = s;
  }
  __syncthreads();          // ONE drain: all gathers + LDS stores land

  // ---- barrier-free K-loop ----
  floatx4 acc[4][4];
  #pragma unroll
  for (int mi = 0; mi < 4; ++mi)
    #pragma unroll
    for (int ni = 0; ni < 4; ++ni) acc[mi][ni] = (floatx4){0.f, 0.f, 0.f, 0.f};

  const int mt0 = wm >> 4;
  #pragma unroll
  for (int kc = 0; kc < 6; ++kc) {
    const int grp = (kc < 2) ? kc : kc - 2;
    #pragma unroll
    for (int ks = 0; ks < 2; ++ks) {
      const int c = ks * 4 + q4;
      half8 a[4];
      if (kc == 2 || kc == 3) {
        const int colbase = (kc - 2) * 64 + ks * 32 + q4 * 8;
        #pragma unroll
        for (int mi = 0; mi < 4; ++mi) {
          float dv = dvals[wm + mi * 16 + l15];
          #pragma unroll
          for (int j = 0; j < 8; ++j)
            a[mi][j] = (half_t)__cosf(__builtin_fmaf(dv, tw_s[colbase + j], tb_s[colbase + j]));
        }
      } else {
        #pragma unroll
        for (int mi = 0; mi < 4; ++mi)
          a[mi] = *(const half8*)(A + grp * 8192 + (((mt0 + mi) * 8 + c) * 16 + l15) * 8);
      }
      const int koff = kc * 64 + ks * 32 + q4 * 8;
      #pragma unroll
      for (int ni = 0; ni < 4; ++ni) {
        half8 b = *(const half8*)(WkvT_l + (size_t)(wn + ni * 16 + l15) * 384 + koff);
        #pragma unroll
        for (int mi = 0; mi < 4; ++mi)
          acc[mi][ni] = __builtin_amdgcn_mfma_f32_16x16x32_f16(a[mi], b, acc[mi][ni], 0, 0, 0);
      }
    }
  }
  __syncthreads();          // align waves before kvT overwrites A region

  // ---- kk -> kvT (cols 0..127) ----
  if (wv < 4) {
    #pragma unroll
    for (int mi = 0; mi < 4; ++mi) {
      int row0 = wm + mi * 16 + q4 * 4;
      if (row0 < 120) {
        #pragma unroll
        for (int ni = 0; ni < 4; ++ni) {
          int col = wn + ni * 16 + l15;
          half4_t h;
          h[0] = (half_t)acc[mi][ni][0]; h[1] = (half_t)acc[mi][ni][1];
          h[2] = (half_t)acc[mi][ni][2]; h[3] = (half_t)acc[mi][ni][3];
          *(half4_t*)(kvT + col * KVPAD + row0) = h;
        }
      }
    }
  }
  __syncthreads();

  // ---- scores ----
  if (tid < 240) {
    int g = tid / 80;
    int rem = tid - g * 80;
    int h = rem / 40;
    int n = rem - h * 40;
    bool masked = (neigh[(bbase + g) * KNN + n] == 0);
    const float* qrow = qs + g * 128 + h * 64;
    int row = g * 40 + n;
    float s = 0.f;
    #pragma unroll 8
    for (int d = 0; d < 64; ++d)
      s += qrow[d] * (float)kvT[(h * 64 + d) * KVPAD + row];
    scs[tid] = masked ? -1e9f : s * 0.125f;
  }
  __syncthreads();

  // ---- softmax (waves 0..5) + vv -> kvT (waves 4..7) ----
  if (wv < 6) {
    float v = (lane < 40) ? scs[wv * 40 + lane] : -1e30f;
    float m = v;
    #pragma unroll
    for (int o = 32; o; o >>= 1) m = fmaxf(m, __shfl_xor(m, o));
    float e = (lane < 40) ? __expf(v - m) : 0.f;
    float ssum = e;
    #pragma unroll
    for (int o = 32; o; o >>= 1) ssum += __shfl_xor(ssum, o);
    if (lane < 40) scs[wv * 40 + lane] = e / ssum;
  }
  if (wv >= 4) {
    #pragma unroll
    for (int mi = 0; mi < 4; ++mi) {
      int row0 = wm + mi * 16 + q4 * 4;
      if (row0 < 120) {
        #pragma unroll
        for (int ni = 0; ni < 4; ++ni) {
          int col = wn - 128 + ni * 16 + l15;
          half4_t h;
          h[0] = (half_t)acc[mi][ni][0]; h[1] = (half_t)acc[mi][ni][1];
          h[2] = (half_t)acc[mi][ni][2]; h[3] = (half_t)acc[mi][ni][3];
          *(half4_t*)(kvT + col * KVPAD + row0) = h;
        }
      }
    }
  }
  __syncthreads();

  // ---- attnOut -> aO16 ----
  if (tid < 384) {
    int g = tid >> 7, dcol = tid & 127, h = dcol >> 6;
    const float* attn = scs + (g * 2 + h) * 40;
    const half_t* vcol = kvT + dcol * KVPAD + g * 40;
    float s = 0.f;
    #pragma unroll 8
    for (int n = 0; n < 40; ++n) s += attn[n] * (float)vcol[n];
    aO16[g * 128 + dcol] = (half_t)s;
  }
  __syncthreads();

  // ---- h1 = relu(attnOut @ Wofc1 + src @ fc1_bot)  (weights from L2) ----
  if (tid < 384) {
    int g = tid >> 7, jj = tid & 127;
    const half_t* srow = nf16 + (size_t)src_idx[bbase + g] * 128;
    float s = 0.f;
    #pragma unroll 8
    for (int d4 = 0; d4 < 32; ++d4) {
      half4_t wa = *(const half4_t*)(W1a4_l + (d4 * 128 + jj) * 4);
      half4_t aa = *(const half4_t*)(aO16 + g * 128 + d4 * 4);
      s = dot4(wa, aa, s);
      half4_t wb = *(const half4_t*)(W1b4_l + (d4 * 128 + jj) * 4);
      half4_t ab = *(const half4_t*)(srow + d4 * 4);
      s = dot4(wb, ab, s);
    }
    h116[g * 128 + jj] = (half_t)fmaxf(s, 0.f);
  }
  __syncthreads();

  // ---- fc2 -> out ----
  if (tid < 384) {
    int g = tid >> 7, ii = tid & 127;
    float s = 0.f;
    #pragma unroll 8
    for (int j4 = 0; j4 < 32; ++j4) {
      half4_t w = *(const half4_t*)(W24_l + (j4 * 128 + ii) * 4);
      half4_t a = *(const half4_t*)(h116 + g * 128 + j4 * 4);
      s = dot4(w, a, s);
    }
    if (L1DIR) out32[(size_t)(bbase + g) * 128 + ii] = s;
    else       out16[(size_t)(bbase + g) * 128 + ii] = (half_t)s;
  }
}

// ---------------------------------------------------------------------------
extern "C" void kernel_launch(void* const* d_in, const int* in_sizes, int n_in,
                              void* d_out, int out_size, void* d_ws, size_t ws_size,
                              hipStream_t stream) {
  const float* nf      = (const float*)d_in[0];
  const float* ef      = (const float*)d_in[1];
  const float* tw      = (const float*)d_in[2];
  const float* tb      = (const float*)d_in[3];
  const float* Wq      = (const float*)d_in[4];
  const float* Wk      = (const float*)d_in[5];
  const float* Wv      = (const float*)d_in[6];
  const float* Wo      = (const float*)d_in[7];
  const float* fc1     = (const float*)d_in[8];
  const float* fc2     = (const float*)d_in[9];
  const int*   srcn    = (const int*)d_in[10];
  const float* ts      = (const float*)d_in[11];
  const int*   neigh2  = (const int*)d_in[12];
  const int*   eidx2   = (const int*)d_in[13];
  const float* etimes2 = (const float*)d_in[14];
  const int*   neigh1  = (const int*)d_in[15];
  const int*   eidx1   = (const int*)d_in[16];
  const float* etimes1 = (const float*)d_in[17];

  char* ws = (char*)d_ws;
  half_t* nf16   = (half_t*)(ws + WS_NF16);
  half_t* emb116 = (half_t*)(ws + WS_EMB16);
  half_t* WkvT16 = (half_t*)(ws + WS_WKVT);
  half_t* Wq4    = (half_t*)(ws + WS_WQ4);
  half_t* W1a4   = (half_t*)(ws + WS_W1A4);
  half_t* W1b4   = (half_t*)(ws + WS_W1B4);
  half_t* W24    = (half_t*)(ws + WS_W24);
  float*  qbias  = (float*)(ws + WS_QBIAS);
  half_t* ef16   = (half_t*)(ws + WS_EF16);
  (void)ws_size;

  cvt_kernel<<<dim3(2048), dim3(256), 0, stream>>>(nf, nf16, 1600000);
  cvt_kernel<<<dim3(4096), dim3(256), 0, stream>>>(ef, ef16, 8000000);
  precompute_w<<<dim3(1281), dim3(256), 0, stream>>>(
      Wq, Wk, Wv, Wo, fc1, fc2, tb, WkvT16, qbias, Wq4, W1a4, W1b4, W24);

  // layer 0: 12000 batches, 3 per block
  hop_kernel<false><<<dim3(4000), dim3(512), 0, stream>>>(
      nf16, nf16, ef16, neigh2, ts, neigh1, eidx1, etimes1, tw, tb,
      Wq4, qbias, WkvT16, W1a4, W1b4, W24, emb116, nullptr);

  // layer 1: 300 batches, 3 per block
  hop_kernel<true><<<dim3(100), dim3(512), 0, stream>>>(
      nf16, emb116, ef16, srcn, ts, neigh2, eidx2, etimes2, tw, tb,
      Wq4 + 16384, qbias + 128, WkvT16 + 98304, W1a4 + 16384, W1b4 + 16384,
      W24 + 16384, emb116, (float*)d_out);
}